// Round 9
// baseline (165.082 us; speedup 1.0000x reference)
//
#include <hip/hip_runtime.h>
#include <math.h>

#define BB 2
#define TT 2048
#define CC 768
#define HH 12
#define HD 64
#define N3 (3*CC)

typedef __attribute__((ext_vector_type(8))) short short8;
typedef __attribute__((ext_vector_type(8))) _Float16 f16x8;
typedef __attribute__((ext_vector_type(4))) float f32x4;
typedef unsigned short u16;

// scale folded into q: 1/sqrt(64) * log2(e)
#define QSCALE 0.1803368809f

static __device__ __forceinline__ u16 f2h(float x) {
    union { _Float16 h; u16 u; } v; v.h = (_Float16)x; return v.u;
}
static __device__ __forceinline__ float ex2(float x) {
#if __has_builtin(__builtin_amdgcn_exp2f)
    return __builtin_amdgcn_exp2f(x);
#else
    return exp2f(x);
#endif
}
// pack two f32 -> 2x fp16 (round-toward-zero), as raw u32
static __device__ __forceinline__ unsigned pk2h(float a, float b) {
    auto p = __builtin_amdgcn_cvt_pkrtz(a, b);   // __fp16 ext_vector(2)
    return __builtin_bit_cast(unsigned, p);
}

// global -> LDS direct copy, 16B per lane. LDS dest = uniform base + lane*16.
static __device__ __forceinline__ void gl16(const void* g, void* l) {
    __builtin_amdgcn_global_load_lds(
        (const __attribute__((address_space(1))) void*)g,
        (__attribute__((address_space(3))) void*)l, 16, 0, 0);
}

// ---------------------------------------------------------------------------
// fused converts: region 0 = x fp32->fp16 plane; regions 1,2 = W transpose.
// ---------------------------------------------------------------------------
__global__ __launch_bounds__(256)
void conv_all(const float* __restrict__ x, u16* __restrict__ xh,
              const float* __restrict__ Wq, u16* __restrict__ wqh,
              const float* __restrict__ Wp, u16* __restrict__ wph)
{
    __shared__ float Tt[64][65];
    const int b = blockIdx.x;
    if (b < 3072) {                      // E/4/256 = 3072 blocks
        const int i = b * 256 + threadIdx.x;
        float4 v = ((const float4*)x)[i];
        ushort4 o;
        o.x = f2h(v.x); o.y = f2h(v.y); o.z = f2h(v.z); o.w = f2h(v.w);
        ((ushort4*)xh)[i] = o;
        return;
    }
    const float* W; u16* T; int N, idx;
    if (b < 3504) { W = Wq; T = wqh; N = N3; idx = b - 3072; }   // 36*12
    else          { W = Wp; T = wph; N = CC; idx = b - 3504; }   // 12*12
    const int ntx = N / 64;
    const int n0 = (idx % ntx) * 64, k0 = (idx / ntx) * 64;
    const int tid = threadIdx.x;
    {
        const int r = tid >> 2, q = tid & 3;
        #pragma unroll
        for (int i = 0; i < 4; ++i) {
            float4 v = *(const float4*)(W + (size_t)(k0 + r) * N + n0 + q * 16 + i * 4);
            Tt[q * 16 + i * 4 + 0][r] = v.x;
            Tt[q * 16 + i * 4 + 1][r] = v.y;
            Tt[q * 16 + i * 4 + 2][r] = v.z;
            Tt[q * 16 + i * 4 + 3][r] = v.w;
        }
    }
    __syncthreads();
    {
        const int n = tid >> 2, q = tid & 3;
        u16 hh[16];
        #pragma unroll
        for (int j = 0; j < 16; ++j) hh[j] = f2h(Tt[n][q * 16 + j]);
        u16* dh = T + (size_t)(n0 + n) * 768 + k0 + q * 16;
        *(short8*)(dh) = *(short8*)&hh[0];
        *(short8*)(dh + 8) = *(short8*)&hh[8];
    }
}

// ---------------------------------------------------------------------------
// fp16 MFMA GEMM, 2-phase prefetch. A [4096][768] fp16 plane,
// B [NCOLS][768] fp16 (pre-transposed). 128x128 tile, BK=32, 4 waves (2x2).
// MODE 0: epilogue -> fp16 q/k/v^T (+bias; q pre-scaled by QSCALE).
// MODE 1: fp32 out (+bias).
// ---------------------------------------------------------------------------
template<int NCOLS, int MODE>
__global__ __launch_bounds__(256)
void mm3(const u16* __restrict__ A_g, const u16* __restrict__ B_g,
         const float* __restrict__ bias, float* __restrict__ outF,
         u16* __restrict__ qo, u16* __restrict__ ko, u16* __restrict__ vto)
{
    __shared__ u16 gsm[16384];     // 32 KB: buf0 {A@0,B@8192}, buf1 @16384
    char* smb = (char*)gsm;
    const int tid = threadIdx.x, lane = tid & 63, wv = tid >> 6;
    const int wm = wv >> 1, wn = wv & 1, r16 = lane & 15, kg = lane >> 4;
    const int m0 = blockIdx.y * 128, n0 = blockIdx.x * 128;

    const u16 *pA[2], *pB[2];
    int ldsq[2];
    #pragma unroll
    for (int qq = 0; qq < 2; ++qq) {
        const int L = wv * 2048 + qq * 1024 + lane * 16;
        const int row = L >> 6, c = (L >> 4) & 3;
        const int cp = c ^ ((row >> 1) & 3);
        ldsq[qq] = wv * 2048 + qq * 1024;
        pA[qq] = A_g + (size_t)(m0 + row) * 768 + cp * 8;
        pB[qq] = B_g + (size_t)(n0 + row) * 768 + cp * 8;
    }

    int aA[4], aB[4];
    #pragma unroll
    for (int t = 0; t < 4; ++t) {
        const int rA = wm * 64 + t * 16 + r16;
        const int rB = wn * 64 + t * 16 + r16;
        aA[t] = rA * 64 + ((kg ^ ((rA >> 1) & 3)) << 4);
        aB[t] = rB * 64 + ((kg ^ ((rB >> 1) & 3)) << 4) + 8192;
    }

    f32x4 acc[4][4];
    #pragma unroll
    for (int i = 0; i < 4; ++i)
        #pragma unroll
        for (int j = 0; j < 4; ++j) acc[i][j] = (f32x4)0.f;

    #pragma unroll
    for (int qq = 0; qq < 2; ++qq) {
        gl16(pA[qq], smb + ldsq[qq]);
        gl16(pB[qq], smb + 8192 + ldsq[qq]);
        pA[qq] += 32; pB[qq] += 32;
    }
    __syncthreads();

    int cur = 0;
    for (int ks = 0; ks < 24; ++ks) {
        const int nxt = cur ^ 1;
        if (ks != 23) {
            #pragma unroll
            for (int qq = 0; qq < 2; ++qq) {
                gl16(pA[qq], smb + nxt * 16384 + ldsq[qq]);
                gl16(pB[qq], smb + nxt * 16384 + 8192 + ldsq[qq]);
                pA[qq] += 32; pB[qq] += 32;
            }
        }
        const int cb = cur * 16384;
        f16x8 a[4], b[4];
        #pragma unroll
        for (int t = 0; t < 4; ++t) {
            a[t] = *(const f16x8*)(smb + cb + aA[t]);
            b[t] = *(const f16x8*)(smb + cb + aB[t]);
        }
        #pragma unroll
        for (int mt = 0; mt < 4; ++mt)
            #pragma unroll
            for (int nt = 0; nt < 4; ++nt)
                acc[mt][nt] = __builtin_amdgcn_mfma_f32_16x16x32_f16(a[mt], b[nt], acc[mt][nt], 0, 0, 0);
        __syncthreads();
        cur = nxt;
    }

    float bi[4];
    #pragma unroll
    for (int nt = 0; nt < 4; ++nt) bi[nt] = bias[n0 + wn * 64 + nt * 16 + r16];

    if (MODE == 1) {
        #pragma unroll
        for (int mt = 0; mt < 4; ++mt)
            #pragma unroll
            for (int nt = 0; nt < 4; ++nt)
                #pragma unroll
                for (int r = 0; r < 4; ++r) {
                    const int grow = m0 + wm * 64 + mt * 16 + kg * 4 + r;
                    const int gcol = n0 + wn * 64 + nt * 16 + r16;
                    outF[(size_t)grow * CC + gcol] = acc[mt][nt][r] + bi[nt];
                }
    } else {
        const int which = n0 / CC;
        const float qsc = (which == 0) ? QSCALE : 1.0f;
        const int b_ = m0 >> 11;
        #pragma unroll
        for (int mt = 0; mt < 4; ++mt) {
            const int tb = ((m0 & 2047) + wm * 64 + mt * 16 + kg * 4);
            #pragma unroll
            for (int nt = 0; nt < 4; ++nt) {
                const int gcol = n0 + wn * 64 + nt * 16 + r16;
                const int cc = gcol - which * CC;
                const int h = cc >> 6, d = cc & 63;
                const int bh_ = b_ * HH + h;
                if (which == 2) {
                    ushort4 hv;
                    #pragma unroll
                    for (int r = 0; r < 4; ++r)
                        ((u16*)&hv)[r] = f2h(acc[mt][nt][r] + bi[nt]);
                    *(ushort4*)(vto + ((size_t)bh_ * 64 + d) * 2048 + tb) = hv;
                } else {
                    u16* dst = (which == 0) ? qo : ko;
                    #pragma unroll
                    for (int r = 0; r < 4; ++r)
                        dst[(((size_t)bh_ * 2048 + tb + r) << 6) + d] =
                            f2h((acc[mt][nt][r] + bi[nt]) * qsc);
                }
            }
        }
    }
}

// ---------------------------------------------------------------------------
// Flash attention, fp16 MFMA, 2-phase prefetch, swapped-QK^T softmax.
// Block = (bh, 128-row q-tile), 4 waves; each wave owns TWO 16-row q-strips
// (A at t0+wv*16, B at t0+64+wv*16) sharing the K/V fragment reads.
// l via ones-column MFMA; defer-max (THR=8, log2 units).
// ---------------------------------------------------------------------------
__global__ __launch_bounds__(256)
void attn3(const u16* __restrict__ qp, const u16* __restrict__ kp,
           const u16* __restrict__ vtp, u16* __restrict__ attp)
{
    __shared__ u16 smem[24576];  // 48KB: buf0{K@0,V@8192} buf1@16384 P@32768(16K)
    char* smb = (char*)smem;

    const int tid = threadIdx.x, bid = blockIdx.x;
    const int qt = 15 - (bid / 24);          // long q-tiles dispatch first
    const int bh = bid % 24;
    const int t0 = qt * 128;
    const int jmax = 2 * qt + 1;
    const int diagA = 2 * qt;
    const int lane = tid & 63, wv = tid >> 6;
    const int r16 = lane & 15, kg = lane >> 4;
    const int r7 = r16 & 7;
    const int kg8 = kg * 8, kg4 = kg * 4;

    // Q fragments (pre-scaled by QSCALE), two strips
    const size_t qroA = ((size_t)bh * TT + t0 + wv * 16 + r16) * 64;
    f16x8 qfA[2], qfB[2];
    #pragma unroll
    for (int ks = 0; ks < 2; ++ks) {
        qfA[ks] = *(const f16x8*)(qp + qroA + ks * 32 + kg8);
        qfB[ks] = *(const f16x8*)(qp + qroA + 4096 + ks * 32 + kg8);
    }
    const int rowA = t0 + wv * 16 + r16;
    const int rowB = rowA + 64;

    // staging pointers (source chunk-swizzled)
    const u16 *pk[2], *pv[2];
    int ldsq[2];
    #pragma unroll
    for (int qq = 0; qq < 2; ++qq) {
        const int L = wv * 2048 + qq * 1024 + lane * 16;
        const int row = L >> 7, c = (L >> 4) & 7;
        const int cp = c ^ (row & 7);
        ldsq[qq] = wv * 2048 + qq * 1024;
        pk[qq] = kp + ((size_t)bh * TT + row) * 64 + cp * 8;     // +4096/tile
        pv[qq] = vtp + ((size_t)bh * 64 + row) * TT + cp * 8;    // +64/tile
    }

    // fragment ds_read byte addrs (buffer-relative, swizzled); K and V^T share
    int aK[2][4], aPA[2], aPB[2];
    #pragma unroll
    for (int ks = 0; ks < 2; ++ks) {
        #pragma unroll
        for (int nt = 0; nt < 4; ++nt) {
            const int row = nt * 16 + r16;
            aK[ks][nt] = row * 128 + (((ks * 4 + kg) ^ (row & 7)) << 4);
        }
        aPA[ks] = 32768 + wv * 2048 + r16 * 128 + (((ks * 4 + kg) ^ r7) << 4);
        aPB[ks] = aPA[ks] + 8192;
    }
    const int pwA = 32768 + wv * 2048 + r16 * 128;
    const int pwB = pwA + 8192;

    f32x4 oA[4], oB[4];
    #pragma unroll
    for (int i = 0; i < 4; ++i) { oA[i] = (f32x4)0.f; oB[i] = (f32x4)0.f; }
    f32x4 lA = (f32x4)0.f, lB = (f32x4)0.f;
    float mA = -1e30f, mB = -1e30f;

    f16x8 ones;
    #pragma unroll
    for (int i = 0; i < 8; ++i) ones[i] = (_Float16)1.0f;

    // prologue: stage tile 0 into buf0
    #pragma unroll
    for (int qq = 0; qq < 2; ++qq) {
        gl16(pk[qq], smb + ldsq[qq]);
        gl16(pv[qq], smb + 8192 + ldsq[qq]);
        pk[qq] += 4096; pv[qq] += 64;
    }
    __syncthreads();

    int cur = 0;
    for (int j = 0; j <= jmax; ++j) {
        const int nxt = cur ^ 1;
        if (j != jmax) {
            #pragma unroll
            for (int qq = 0; qq < 2; ++qq) {
                gl16(pk[qq], smb + nxt * 16384 + ldsq[qq]);
                gl16(pv[qq], smb + nxt * 16384 + 8192 + ldsq[qq]);
                pk[qq] += 4096; pv[qq] += 64;
            }
        }
        const int cb = cur * 16384;
        const int kb = j * 64;

        // S^T for both strips, sharing kf reads
        f32x4 sA[4], sB[4];
        #pragma unroll
        for (int nt = 0; nt < 4; ++nt) { sA[nt] = (f32x4)0.f; sB[nt] = (f32x4)0.f; }
        __builtin_amdgcn_s_setprio(1);
        #pragma unroll
        for (int ks = 0; ks < 2; ++ks)
            #pragma unroll
            for (int nt = 0; nt < 4; ++nt) {
                f16x8 kf = *(const f16x8*)(smb + cb + aK[ks][nt]);
                sA[nt] = __builtin_amdgcn_mfma_f32_16x16x32_f16(kf, qfA[ks], sA[nt], 0, 0, 0);
                sB[nt] = __builtin_amdgcn_mfma_f32_16x16x32_f16(kf, qfB[ks], sB[nt], 0, 0, 0);
            }
        __builtin_amdgcn_s_setprio(0);

        // causal masks (absolute): key kb+nt*16+kg4+r vs row
        if (j >= diagA) {
            #pragma unroll
            for (int nt = 0; nt < 4; ++nt)
                #pragma unroll
                for (int r = 0; r < 4; ++r)
                    if (kb + nt * 16 + kg4 + r > rowA) sA[nt][r] = -1e30f;
        }
        if (j == jmax) {
            #pragma unroll
            for (int nt = 0; nt < 4; ++nt)
                #pragma unroll
                for (int r = 0; r < 4; ++r)
                    if (kb + nt * 16 + kg4 + r > rowB) sB[nt][r] = -1e30f;
        }

        // softmax per strip (row = own q-row, keys in-lane)
        auto softmax = [&](f32x4 (&s)[4], float& m, f32x4& ol, f32x4 (&oa)[4],
                           int pwbase) {
            float pm = s[0][0];
            #pragma unroll
            for (int nt = 0; nt < 4; ++nt)
                #pragma unroll
                for (int r = 0; r < 4; ++r)
                    if (nt | r) pm = fmaxf(pm, s[nt][r]);
            pm = fmaxf(pm, __shfl_xor(pm, 16));
            pm = fmaxf(pm, __shfl_xor(pm, 32));
            if (__any(pm > m + 8.0f)) {
                const float mn = fmaxf(m, pm);
                const float corr = ex2(m - mn);
                m = mn;
                const float c0 = __shfl(corr, kg4 + 0);
                const float c1 = __shfl(corr, kg4 + 1);
                const float c2 = __shfl(corr, kg4 + 2);
                const float c3 = __shfl(corr, kg4 + 3);
                #pragma unroll
                for (int nt = 0; nt < 4; ++nt) {
                    oa[nt][0] *= c0; oa[nt][1] *= c1;
                    oa[nt][2] *= c2; oa[nt][3] *= c3;
                }
                ol[0] *= c0; ol[1] *= c1; ol[2] *= c2; ol[3] *= c3;
            }
            #pragma unroll
            for (int nt = 0; nt < 4; ++nt) {
                const float p0 = ex2(s[nt][0] - m), p1 = ex2(s[nt][1] - m);
                const float p2 = ex2(s[nt][2] - m), p3 = ex2(s[nt][3] - m);
                uint2 w;
                w.x = pk2h(p0, p1);
                w.y = pk2h(p2, p3);
                *(uint2*)(smb + pwbase + ((nt * 32 + kg8) ^ (r7 << 4))) = w;
            }
        };
        softmax(sA, mA, lA, oA, pwA);
        softmax(sB, mB, lB, oB, pwB);

        // O += P @ V for both strips, sharing vf reads; l += P @ ones
        __builtin_amdgcn_s_setprio(1);
        #pragma unroll
        for (int ks = 0; ks < 2; ++ks) {
            f16x8 paA = *(const f16x8*)(smb + aPA[ks]);
            f16x8 paB = *(const f16x8*)(smb + aPB[ks]);
            lA = __builtin_amdgcn_mfma_f32_16x16x32_f16(paA, ones, lA, 0, 0, 0);
            lB = __builtin_amdgcn_mfma_f32_16x16x32_f16(paB, ones, lB, 0, 0, 0);
            #pragma unroll
            for (int nt = 0; nt < 4; ++nt) {
                f16x8 vf = *(const f16x8*)(smb + cb + 8192 + aK[ks][nt]);
                oA[nt] = __builtin_amdgcn_mfma_f32_16x16x32_f16(paA, vf, oA[nt], 0, 0, 0);
                oB[nt] = __builtin_amdgcn_mfma_f32_16x16x32_f16(paB, vf, oB[nt], 0, 0, 0);
            }
        }
        __builtin_amdgcn_s_setprio(0);

        __syncthreads();
        cur = nxt;
    }

    // epilogue: normalize, write att fp16 plane [B*T][C], both strips
    const int b_ = bh / HH, h = bh % HH;
    #pragma unroll
    for (int r = 0; r < 4; ++r) {
        const float invA = 1.f / lA[r];
        const float invB = 1.f / lB[r];
        const int tA = t0 + wv * 16 + kg4 + r;
        const size_t baseA = ((size_t)b_ * TT + tA) * CC + h * 64;
        const size_t baseB = baseA + (size_t)64 * CC;
        #pragma unroll
        for (int nt = 0; nt < 4; ++nt) {
            attp[baseA + nt * 16 + r16] = f2h(oA[nt][r] * invA);
            attp[baseB + nt * 16 + r16] = f2h(oB[nt][r] * invB);
        }
    }
}

// ---------------------------------------------------------------------------
extern "C" void kernel_launch(void* const* d_in, const int* in_sizes, int n_in,
                              void* d_out, int out_size, void* d_ws, size_t ws_size,
                              hipStream_t stream)
{
    const float* x     = (const float*)d_in[0];
    const float* Wqkv  = (const float*)d_in[1];
    const float* bqkv  = (const float*)d_in[2];
    const float* Wproj = (const float*)d_in[3];
    const float* bproj = (const float*)d_in[4];
    float* out = (float*)d_out;

    const size_t E  = (size_t)4096 * 768;        // 3,145,728
    const size_t WQ = (size_t)2304 * 768;
    const size_t WP = (size_t)768 * 768;

    u16* ws   = (u16*)d_ws;
    u16* xh   = ws;            // x plane; aliased by att plane after qkv GEMM
    u16* atth = ws;
    u16* wqh  = ws + E;
    u16* wph  = wqh + WQ;
    u16* qh   = wph + WP;
    u16* kh   = qh + E;
    u16* vth  = kh + E;

    conv_all<<<dim3(3648), 256, 0, stream>>>(x, xh, Wqkv, wqh, Wproj, wph);

    mm3<N3, 0><<<dim3(N3 / 128, 32), 256, 0, stream>>>(
        xh, wqh, bqkv, nullptr, qh, kh, vth);
    attn3<<<dim3(384), 256, 0, stream>>>(qh, kh, vth, atth);
    mm3<CC, 1><<<dim3(CC / 128, 32), 256, 0, stream>>>(
        atth, wph, bproj, out, nullptr, nullptr, nullptr);
}